// Round 9
// baseline (29.011 us; speedup 1.0000x reference)
//
#include <hip/hip_runtime.h>

// GradientFusionloss: loss = mean(|grad(gen_y) - max(grad(vis_y), grad(ir))|)
// grad(I) = |sobel_x(I)| + |sobel_y(I)|, zero-padded 3x3 cross-correlation.
// Shapes: vis (32,3,512,512) f32, ir (32,1,512,512) f32, gen (32,3,512,512) f32.
// Only channel 0 of vis/gen is read. Output: 1 fp32 scalar.
//
// R8: wave-count is the binding constraint (R1: 8 waves/CU -> 0.97 TB/s;
// R0: 16 waves/CU -> 2.6 TB/s; ~linear). 4px/thread fixes total waves at
// 4096 = 16/CU (grid-limited). Go 2px/thread (ROWS=8 kept): 8192 waves =
// 32/CU ceiling, Row=4 floats drops VGPR to ~75 so ~24-28/CU effective.
// VMEM instr count doubles but TA estimate (~7us) < memory floor (~14us).
// Failed (do not revisit): fused atomic finalize (R3/R4), ROWS=16 (R1),
// ROWS=4 (R5), shfl halos (R6), VGPR caps (R2), sw prefetch (R7 neutral).

#define IMG_H 512
#define IMG_W 512
#define BATCH 32
#define ROWS 8                 // rows per thread strip (10/8 row halo)
#define PX 2                   // pixels per thread in x
#define XT (IMG_W / PX)        // 256 x-tiles
#define STRIPS (IMG_H / ROWS)  // 64
#define THREADS 256
#define TOTAL_THREADS (BATCH * STRIPS * XT)     // 524288
#define NBLOCKS (TOTAL_THREADS / THREADS)       // 2048
#define NPIX ((double)BATCH * IMG_H * IMG_W)

struct Row { float l, x, y, r; };   // halo-left, px0, px1, halo-right

__device__ __forceinline__ void zero_row(Row& r) {
    r.l = r.x = r.y = r.r = 0.0f;
}

__device__ __forceinline__ void load_row(const float* __restrict__ p, int xb,
                                         bool hl, bool hr, Row& r) {
    float2 v = *reinterpret_cast<const float2*>(p + xb);
    r.x = v.x; r.y = v.y;
    r.l = hl ? p[xb - 1] : 0.0f;   // L1-hit: line fetched by neighbor lane
    r.r = hr ? p[xb + 2] : 0.0f;
}

// element j of the 4-wide register row, j in [-1, 2]; j is compile-time
__device__ __forceinline__ float gete(const Row& r, int j) {
    switch (j) {
        case -1: return r.l;
        case 0:  return r.x;
        case 1:  return r.y;
        default: return r.r;
    }
}

// |sobel_x| + |sobel_y| at column j of the 2-wide tile (XLA conv = correlation)
__device__ __forceinline__ float sobel_grad(const Row& t, const Row& m, const Row& b, int j) {
    float a  = gete(t, j - 1), bb = gete(t, j), c  = gete(t, j + 1);
    float d  = gete(m, j - 1),                  f  = gete(m, j + 1);
    float g  = gete(b, j - 1), hh = gete(b, j), i2 = gete(b, j + 1);
    float gx = (c - a) + 2.0f * (f - d) + (i2 - g);
    float gy = (a + 2.0f * bb + c) - (g + 2.0f * hh + i2);
    return fabsf(gx) + fabsf(gy);
}

__global__ __launch_bounds__(THREADS)
void grad_loss_kernel(const float* __restrict__ vis, const float* __restrict__ ir,
                      const float* __restrict__ gen, float* __restrict__ partial) {
    int t    = blockIdx.x * THREADS + threadIdx.x;
    int xt   = t & (XT - 1);
    int rest = t >> 8;
    int ys   = rest & (STRIPS - 1);
    int b    = rest >> 6;

    const float* pv = vis + (size_t)b * 3 * IMG_H * IMG_W;  // channel 0
    const float* pi = ir  + (size_t)b * IMG_H * IMG_W;
    const float* pg = gen + (size_t)b * 3 * IMG_H * IMG_W;  // channel 0

    int  xb = xt * PX;
    bool hl = (xt != 0), hr = (xt != XT - 1);
    int  y0 = ys * ROWS;

    // Rolling window: *m = row y-1, *z = row y, *1 = row y+1, *n = incoming y+2
    Row vm, vz, v1, vn, im, iz, i1, in_, gm, gz, g1, gn;
    if (y0 == 0) {
        zero_row(vm); zero_row(im); zero_row(gm);
    } else {
        load_row(pv + (size_t)(y0 - 1) * IMG_W, xb, hl, hr, vm);
        load_row(pi + (size_t)(y0 - 1) * IMG_W, xb, hl, hr, im);
        load_row(pg + (size_t)(y0 - 1) * IMG_W, xb, hl, hr, gm);
    }
    load_row(pv + (size_t)y0 * IMG_W, xb, hl, hr, vz);
    load_row(pi + (size_t)y0 * IMG_W, xb, hl, hr, iz);
    load_row(pg + (size_t)y0 * IMG_W, xb, hl, hr, gz);
    load_row(pv + (size_t)(y0 + 1) * IMG_W, xb, hl, hr, v1);
    load_row(pi + (size_t)(y0 + 1) * IMG_W, xb, hl, hr, i1);
    load_row(pg + (size_t)(y0 + 1) * IMG_W, xb, hl, hr, g1);

    float acc = 0.0f;
    #pragma unroll
    for (int r = 0; r < ROWS; ++r) {
        int y = y0 + r;
        // Prefetch row y+2 (consumed next iteration); wave-uniform guard
        // doubles as bottom-edge zero padding.
        if (y + 2 < IMG_H) {
            load_row(pv + (size_t)(y + 2) * IMG_W, xb, hl, hr, vn);
            load_row(pi + (size_t)(y + 2) * IMG_W, xb, hl, hr, in_);
            load_row(pg + (size_t)(y + 2) * IMG_W, xb, hl, hr, gn);
        } else {
            zero_row(vn); zero_row(in_); zero_row(gn);
        }
        #pragma unroll
        for (int j = 0; j < PX; ++j) {
            float ggen = sobel_grad(gm, gz, g1, j);
            float gvis = sobel_grad(vm, vz, v1, j);
            float gir  = sobel_grad(im, iz, i1, j);
            acc += fabsf(ggen - fmaxf(gvis, gir));
        }
        vm = vz; vz = v1; v1 = vn;
        im = iz; iz = i1; i1 = in_;
        gm = gz; gz = g1; g1 = gn;
    }

    // block reduction (fixed order -> deterministic)
    #pragma unroll
    for (int off = 32; off > 0; off >>= 1)
        acc += __shfl_down(acc, off, 64);
    __shared__ float s[THREADS / 64];
    int lane = threadIdx.x & 63, wid = threadIdx.x >> 6;
    if (lane == 0) s[wid] = acc;
    __syncthreads();
    if (threadIdx.x == 0)
        partial[blockIdx.x] = s[0] + s[1] + s[2] + s[3];
}

__global__ __launch_bounds__(THREADS)
void reduce_kernel(const float* __restrict__ partial, float* __restrict__ out) {
    float acc = 0.0f;
    #pragma unroll
    for (int i = 0; i < NBLOCKS / THREADS; ++i)   // fixed order -> deterministic
        acc += partial[threadIdx.x + i * THREADS];
    #pragma unroll
    for (int off = 32; off > 0; off >>= 1)
        acc += __shfl_down(acc, off, 64);
    __shared__ float s[THREADS / 64];
    int lane = threadIdx.x & 63, wid = threadIdx.x >> 6;
    if (lane == 0) s[wid] = acc;
    __syncthreads();
    if (threadIdx.x == 0)
        out[0] = (float)((s[0] + s[1] + s[2] + s[3]) * (1.0 / NPIX));
}

extern "C" void kernel_launch(void* const* d_in, const int* in_sizes, int n_in,
                              void* d_out, int out_size, void* d_ws, size_t ws_size,
                              hipStream_t stream) {
    const float* vis = (const float*)d_in[0];
    const float* ir  = (const float*)d_in[1];
    const float* gen = (const float*)d_in[2];
    float* out       = (float*)d_out;
    float* partial   = (float*)d_ws;   // NBLOCKS floats = 8 KiB

    grad_loss_kernel<<<NBLOCKS, THREADS, 0, stream>>>(vis, ir, gen, partial);
    reduce_kernel<<<1, THREADS, 0, stream>>>(partial, out);
}